// Round 1
// baseline (3303.854 us; speedup 1.0000x reference)
//
#include <hip/hip_runtime.h>

typedef unsigned long long u64;
typedef unsigned int u32;

#define NB   8
#define NPC  8192
#define SS   2048
#define KK   32
#define CIN  64
#define NQ   (NB*SS)              // 16384
#define POS_OUT_OFF   (NQ*128)
#define BATCH_OUT_OFF (NQ*128 + NQ*3)

// ---------------- Kernel 1: exact farthest point sampling -------------------
// One block per cloud. 512 threads x 16 points in registers. Exact f32 ops
// (no FMA contraction) to bit-match the numpy/jax f32 reference; argmax ties
// break to lowest index via key low word = ~gidx.
__global__ __launch_bounds__(512) void fps_kernel(const float* __restrict__ pos,
                                                  float* __restrict__ out)
{
    __shared__ float lp[NPC*3];
    __shared__ u64 red[2][8];
    const int tid  = threadIdx.x;
    const int wid  = tid >> 6;
    const int lane = tid & 63;
    const int cloud = blockIdx.x;
    const float* cp = pos + (size_t)cloud * (NPC*3);

    {   // stage cloud positions into LDS (coalesced float4)
        const float4* s4 = (const float4*)cp;
        float4* d4 = (float4*)lp;
        #pragma unroll
        for (int i = 0; i < 12; ++i) d4[tid + i*512] = s4[tid + i*512];
    }
    __syncthreads();

    float px[16], py[16], pz[16], mind[16];
    #pragma unroll
    for (int k = 0; k < 16; ++k) {
        int j = tid*16 + k;
        px[k] = lp[j*3+0]; py[k] = lp[j*3+1]; pz[k] = lp[j*3+2];
        mind[k] = __int_as_float(0x7f800000);   // +inf
    }

    float cx = lp[0], cy = lp[1], cz = lp[2];   // center 0 = point 0

    float* qout = out + POS_OUT_OFF   + (size_t)cloud * SS * 3;
    float* bout = out + BATCH_OUT_OFF + (size_t)cloud * SS;

    for (int s = 0; s < SS; ++s) {
        if (tid == 0) {
            qout[s*3+0] = cx; qout[s*3+1] = cy; qout[s*3+2] = cz;
            bout[s] = (float)cloud;
        }
        // update mind with distance to current center; local argmax (lowest k on tie)
        float bm = -1.0f; int bk = 0;
        #pragma unroll
        for (int k = 0; k < 16; ++k) {
            float dx = __fsub_rn(px[k], cx);
            float dy = __fsub_rn(py[k], cy);
            float dz = __fsub_rn(pz[k], cz);
            float d  = __fadd_rn(__fadd_rn(__fmul_rn(dx,dx), __fmul_rn(dy,dy)), __fmul_rn(dz,dz));
            float m  = fminf(mind[k], d);
            mind[k] = m;
            if (m > bm) { bm = m; bk = k; }
        }
        u64 key = ((u64)__float_as_uint(bm) << 32) | (u32)(~(u32)(tid*16 + bk));
        #pragma unroll
        for (int off = 32; off >= 1; off >>= 1) {
            u64 o = __shfl_xor(key, off);
            if (o > key) key = o;
        }
        if (lane == 0) red[s&1][wid] = key;
        __syncthreads();
        u64 g = red[s&1][0];
        #pragma unroll
        for (int w = 1; w < 8; ++w) { u64 o = red[s&1][w]; if (o > g) g = o; }
        u32 widx = ~(u32)g;                    // winning point index in cloud
        cx = lp[widx*3+0]; cy = lp[widx*3+1]; cz = lp[widx*3+2];
    }
}

// ---------------- Kernel 2: radius / 32 smallest-d2 selection ---------------
// key = (d2_bits<<32)|idx : 32 smallest keys == top_k(-d2) with stable ties.
#define CAND_MAX 640
__global__ __launch_bounds__(256) void radius_kernel(const float* __restrict__ pos,
                                                     const float* __restrict__ out,
                                                     int* __restrict__ nidx,
                                                     int* __restrict__ ncnt)
{
    __shared__ float lp[NPC*3];
    __shared__ u64 cand[4][CAND_MAX];
    const int tid  = threadIdx.x;
    const int wid  = tid >> 6;
    const int lane = tid & 63;
    const int cloud = blockIdx.x >> 6;          // 64 blocks per cloud
    const int qbase = (blockIdx.x & 63) * 32;
    const float R2 = (float)(0.2 * 0.2);        // float32(0.04) = 0x3D23D70A, matches ref

    const float* cp = pos + (size_t)cloud * (NPC*3);
    {
        const float4* s4 = (const float4*)cp;
        float4* d4 = (float4*)lp;
        #pragma unroll
        for (int i = 0; i < 24; ++i) d4[tid + i*256] = s4[tid + i*256];
    }
    __syncthreads();

    const float* qpos = out + POS_OUT_OFF;
    u64* cw = cand[wid];

    for (int qq = 0; qq < 8; ++qq) {
        int q   = qbase + wid*8 + qq;
        int qid = cloud*SS + q;
        float qx = qpos[qid*3+0], qy = qpos[qid*3+1], qz = qpos[qid*3+2];

        int m = 0;
        for (int c = 0; c < NPC/64; ++c) {
            int j = c*64 + lane;
            float dx = __fsub_rn(lp[j*3+0], qx);
            float dy = __fsub_rn(lp[j*3+1], qy);
            float dz = __fsub_rn(lp[j*3+2], qz);
            float d2 = __fadd_rn(__fadd_rn(__fmul_rn(dx,dx), __fmul_rn(dy,dy)), __fmul_rn(dz,dz));
            bool in = (d2 <= R2);
            u64 mk = __ballot(in);
            if (in) {
                int p = m + __popcll(mk & ((1ull << lane) - 1ull));
                if (p < CAND_MAX) cw[p] = ((u64)__float_as_uint(d2) << 32) | (u32)j;
            }
            m += __popcll(mk);
        }
        if (m > CAND_MAX) m = CAND_MAX;

        u64 kk[10];
        #pragma unroll
        for (int t = 0; t < 10; ++t) {
            int p = t*64 + lane;
            u64 v = cw[p];
            kk[t] = (p < m) ? v : ~0ull;
        }
        int cq = (m < KK) ? m : KK;
        int* nq = nidx + (size_t)qid * KK;
        int j0 = 0;
        #pragma unroll 1
        for (int r = 0; r < KK; ++r) {
            u64 lmin = kk[0];
            #pragma unroll
            for (int t = 1; t < 10; ++t) if (kk[t] < lmin) lmin = kk[t];
            #pragma unroll
            for (int off = 32; off >= 1; off >>= 1) {
                u64 o = __shfl_xor(lmin, off);
                if (o < lmin) lmin = o;
            }
            int j = (int)(u32)(lmin & 0xffffffffull);
            if (r == 0) j0 = j;                 // center itself (d2 = 0) is always first
            if (lane == 0) nq[r] = (lmin == ~0ull) ? j0 : j;
            #pragma unroll
            for (int t = 0; t < 10; ++t) if (kk[t] == lmin) kk[t] = ~0ull;
        }
        if (lane == 0) ncnt[qid] = cq;
    }
}

// ---------------- Kernel 3: gather + 3-layer MLP + masked max ---------------
// thread = (query, neighbor slot). feat in padded LDS (stride 69: conflict-free),
// weights in LDS (broadcast reads), 64 fp32 accumulators in registers.
__global__ __launch_bounds__(256) void mlp_kernel(const float* __restrict__ x,
                                                  const float* __restrict__ pos,
                                                  const float* __restrict__ W1, const float* __restrict__ b1,
                                                  const float* __restrict__ W2, const float* __restrict__ b2,
                                                  const float* __restrict__ W3, const float* __restrict__ b3,
                                                  const int* __restrict__ nidx, const int* __restrict__ ncnt,
                                                  float* __restrict__ out)
{
    __shared__ float w1[67*64];
    __shared__ float w2[64*64];
    __shared__ float w3[64*128];
    __shared__ float bias[64+64+128];
    __shared__ float flds[256*69];

    const int tid = threadIdx.x;
    for (int i = tid; i < 67*64;  i += 256) w1[i] = W1[i];
    for (int i = tid; i < 64*64;  i += 256) w2[i] = W2[i];
    for (int i = tid; i < 64*128; i += 256) w3[i] = W3[i];
    if (tid < 64)  bias[tid]      = b1[tid];
    if (tid < 64)  bias[64+tid]   = b2[tid];
    if (tid < 128) bias[128+tid]  = b3[tid];
    __syncthreads();

    const int q     = blockIdx.x * 8 + (tid >> 5);
    const int slot  = tid & 31;
    const int cloud = q >> 11;
    const int j     = nidx[q*KK + slot];
    const bool valid = slot < ncnt[q];
    const size_t row = (size_t)cloud * NPC + (size_t)j;

    const float* qp = out + POS_OUT_OFF + (size_t)q*3;
    float qx = qp[0], qy = qp[1], qz = qp[2];

    float* myf = &flds[tid*69];
    {
        const float4* xr = (const float4*)(x + row*CIN);
        #pragma unroll
        for (int i = 0; i < 16; ++i) {
            float4 v = xr[i];
            myf[i*4+0]=v.x; myf[i*4+1]=v.y; myf[i*4+2]=v.z; myf[i*4+3]=v.w;
        }
        myf[64] = __fsub_rn(pos[row*3+0], qx);
        myf[65] = __fsub_rn(pos[row*3+1], qy);
        myf[66] = __fsub_rn(pos[row*3+2], qz);
    }
    // each thread reads only its own flds region: no barrier needed

    float acc[64];
    // ----- layer 1: 67 -> 64, relu -----
    #pragma unroll
    for (int o = 0; o < 64; ++o) acc[o] = bias[o];
    for (int i = 0; i < 67; ++i) {
        float f = myf[i];
        #pragma unroll
        for (int o = 0; o < 64; o += 4) {
            const float4 wv = *(const float4*)&w1[i*64+o];
            acc[o+0] = fmaf(f, wv.x, acc[o+0]);
            acc[o+1] = fmaf(f, wv.y, acc[o+1]);
            acc[o+2] = fmaf(f, wv.z, acc[o+2]);
            acc[o+3] = fmaf(f, wv.w, acc[o+3]);
        }
    }
    #pragma unroll
    for (int o = 0; o < 64; ++o) myf[o] = fmaxf(acc[o], 0.0f);

    // ----- layer 2: 64 -> 64, relu -----
    #pragma unroll
    for (int o = 0; o < 64; ++o) acc[o] = bias[64+o];
    for (int i = 0; i < 64; ++i) {
        float f = myf[i];
        #pragma unroll
        for (int o = 0; o < 64; o += 4) {
            const float4 wv = *(const float4*)&w2[i*64+o];
            acc[o+0] = fmaf(f, wv.x, acc[o+0]);
            acc[o+1] = fmaf(f, wv.y, acc[o+1]);
            acc[o+2] = fmaf(f, wv.z, acc[o+2]);
            acc[o+3] = fmaf(f, wv.w, acc[o+3]);
        }
    }
    #pragma unroll
    for (int o = 0; o < 64; ++o) myf[o] = fmaxf(acc[o], 0.0f);

    // ----- layer 3: 64 -> 128 (two 64-wide halves), mask, max over 32 slots -----
    float* orow = out + (size_t)q*128;
    const float NEGINF = __int_as_float(0xff800000);
    for (int h = 0; h < 2; ++h) {
        #pragma unroll
        for (int o = 0; o < 64; ++o) acc[o] = bias[128 + h*64 + o];
        const float* w3h = w3 + h*64;
        for (int i = 0; i < 64; ++i) {
            float f = myf[i];
            #pragma unroll
            for (int o = 0; o < 64; o += 4) {
                const float4 wv = *(const float4*)&w3h[i*128+o];
                acc[o+0] = fmaf(f, wv.x, acc[o+0]);
                acc[o+1] = fmaf(f, wv.y, acc[o+1]);
                acc[o+2] = fmaf(f, wv.z, acc[o+2]);
                acc[o+3] = fmaf(f, wv.w, acc[o+3]);
            }
        }
        #pragma unroll
        for (int o = 0; o < 64; ++o) if (!valid) acc[o] = NEGINF;
        #pragma unroll
        for (int off = 16; off >= 1; off >>= 1) {
            #pragma unroll
            for (int o = 0; o < 64; ++o) acc[o] = fmaxf(acc[o], __shfl_xor(acc[o], off));
        }
        if (slot == 0) {
            #pragma unroll
            for (int o = 0; o < 64; o += 4) {
                float4 v = make_float4(acc[o], acc[o+1], acc[o+2], acc[o+3]);
                *(float4*)&orow[h*64+o] = v;
            }
        }
    }
}

// ------------------------------- launcher -----------------------------------
extern "C" void kernel_launch(void* const* d_in, const int* in_sizes, int n_in,
                              void* d_out, int out_size, void* d_ws, size_t ws_size,
                              hipStream_t stream) {
    const float* x   = (const float*)d_in[0];
    const float* pos = (const float*)d_in[1];
    // d_in[2]=batch (implicit), d_in[3]=num_samples (K=32 hardcoded)
    const float* W1 = (const float*)d_in[4];
    const float* b1 = (const float*)d_in[5];
    const float* W2 = (const float*)d_in[6];
    const float* b2 = (const float*)d_in[7];
    const float* W3 = (const float*)d_in[8];
    const float* b3 = (const float*)d_in[9];
    float* out = (float*)d_out;

    int* nidx = (int*)d_ws;                  // NQ*KK ints (2 MiB)
    int* ncnt = nidx + (size_t)NQ*KK;        // NQ ints

    hipLaunchKernelGGL(fps_kernel,    dim3(NB),    dim3(512), 0, stream, pos, out);
    hipLaunchKernelGGL(radius_kernel, dim3(512),   dim3(256), 0, stream, pos, out, nidx, ncnt);
    hipLaunchKernelGGL(mlp_kernel,    dim3(NQ/8),  dim3(256), 0, stream,
                       x, pos, W1, b1, W2, b2, W3, b3, nidx, ncnt, out);
}

// Round 2
// 2522.089 us; speedup vs baseline: 1.3100x; 1.3100x over previous
//
#include <hip/hip_runtime.h>

typedef unsigned long long u64;
typedef unsigned int u32;
typedef float v2f __attribute__((ext_vector_type(2)));

#define NB   8
#define NPC  8192
#define SS   2048
#define KK   32
#define CIN  64
#define NQ   (NB*SS)              // 16384
#define POS_OUT_OFF   (NQ*128)
#define BATCH_OUT_OFF (NQ*128 + NQ*3)
#define INF64 0x7ff0000000000000ULL

// Packed f32 ops via inline asm: IEEE round-to-nearest-even, bit-identical to
// scalar v_add_f32/v_mul_f32 per half; immune to -ffp-contract fusing.
__device__ __forceinline__ v2f pk_add(v2f a, v2f b) {
    v2f r; asm("v_pk_add_f32 %0, %1, %2" : "=v"(r) : "v"(a), "v"(b)); return r;
}
__device__ __forceinline__ v2f pk_mul(v2f a, v2f b) {
    v2f r; asm("v_pk_mul_f32 %0, %1, %2" : "=v"(r) : "v"(a), "v"(b)); return r;
}
// key = (dist_bits<<32) | ~idx, viewed as f64. dist_bits <= 0x7f800000 so the
// f64 exponent field is < 2047: never NaN/Inf -> v_max_f64 == exact u64 max.
__device__ __forceinline__ double mkkey(float m, u32 ni) {
    return __longlong_as_double((long long)(((u64)__float_as_uint(m) << 32) | (u64)ni));
}

// ---------------- Kernel 1: exact farthest point sampling -------------------
// One block/cloud, 512 thr x 16 pts. No global stores in the step loop (winner
// history kept in LDS); packed-f32 distance update; f64-key max reduction.
__global__ __launch_bounds__(512) void fps_kernel(const float* __restrict__ pos,
                                                  float* __restrict__ out)
{
    __shared__ float lp[NPC*3];
    __shared__ double red[2][8];
    __shared__ unsigned short hist[SS];
    const int tid  = threadIdx.x;
    const int wid  = tid >> 6;
    const int lane = tid & 63;
    const int cloud = blockIdx.x;
    const float* cp = pos + (size_t)cloud * (NPC*3);

    {   // stage cloud positions into LDS (coalesced float4)
        const float4* s4 = (const float4*)cp;
        float4* d4 = (float4*)lp;
        #pragma unroll
        for (int i = 0; i < 12; ++i) d4[tid + i*512] = s4[tid + i*512];
    }
    __syncthreads();

    v2f px[8], py[8], pz[8], mind[8];
    u32 inv[16];
    const float finf = __int_as_float(0x7f800000);
    #pragma unroll
    for (int k = 0; k < 8; ++k) {
        int j = tid*16 + 2*k;
        px[k] = (v2f){lp[j*3+0], lp[j*3+3]};
        py[k] = (v2f){lp[j*3+1], lp[j*3+4]};
        pz[k] = (v2f){lp[j*3+2], lp[j*3+5]};
        mind[k] = (v2f){finf, finf};
    }
    #pragma unroll
    for (int k = 0; k < 16; ++k) inv[k] = ~(u32)(tid*16 + k);

    float cx = lp[0], cy = lp[1], cz = lp[2];
    u32 widx = 0;

    for (int s = 0; s < SS; ++s) {
        if (tid == 0) hist[s] = (unsigned short)widx;
        // p + (-c) rounds identically to p - c (exact sign-flip on c)
        v2f ncx = (v2f){-cx,-cx}, ncy = (v2f){-cy,-cy}, ncz = (v2f){-cz,-cz};
        double kd[16];
        #pragma unroll
        for (int k = 0; k < 8; ++k) {
            v2f dx = pk_add(px[k], ncx);
            v2f dy = pk_add(py[k], ncy);
            v2f dz = pk_add(pz[k], ncz);
            v2f d  = pk_add(pk_add(pk_mul(dx,dx), pk_mul(dy,dy)), pk_mul(dz,dz));
            float m0 = fminf(mind[k].x, d.x);
            float m1 = fminf(mind[k].y, d.y);
            mind[k].x = m0; mind[k].y = m1;
            kd[2*k]   = mkkey(m0, inv[2*k]);
            kd[2*k+1] = mkkey(m1, inv[2*k+1]);
        }
        #pragma unroll
        for (int st = 8; st >= 1; st >>= 1) {
            #pragma unroll
            for (int k = 0; k < st; ++k) kd[k] = fmax(kd[k], kd[k+st]);
        }
        double wk = kd[0];
        #pragma unroll
        for (int off = 32; off >= 1; off >>= 1)
            wk = fmax(wk, __shfl_xor(wk, off));
        if (lane == 0) red[s&1][wid] = wk;
        __syncthreads();
        const double* rb = red[s&1];
        double g = fmax(fmax(fmax(rb[0],rb[1]), fmax(rb[2],rb[3])),
                        fmax(fmax(rb[4],rb[5]), fmax(rb[6],rb[7])));
        widx = ~(u32)((u64)__double_as_longlong(g));
        cx = lp[widx*3+0]; cy = lp[widx*3+1]; cz = lp[widx*3+2];
    }
    __syncthreads();

    float* qout = out + POS_OUT_OFF   + (size_t)cloud * SS * 3;
    float* bout = out + BATCH_OUT_OFF + (size_t)cloud * SS;
    for (int s = tid; s < SS; s += 512) {
        u32 w = hist[s];
        qout[s*3+0] = lp[w*3+0];
        qout[s*3+1] = lp[w*3+1];
        qout[s*3+2] = lp[w*3+2];
        bout[s] = (float)cloud;
    }
}

// ---------------- Kernel 2: radius / 32 smallest-d2 selection ---------------
// Global-direct scan (cloud is L2-resident across the 64 blocks sharing it),
// ballot-compacted candidates in LDS, f64-key min extraction.
#define CAND_MAX 640
__global__ __launch_bounds__(256) void radius_kernel(const float* __restrict__ pos,
                                                     const float* __restrict__ out,
                                                     int* __restrict__ nidx,
                                                     int* __restrict__ ncnt)
{
    __shared__ u64 cand[4][CAND_MAX];
    const int tid  = threadIdx.x;
    const int wid  = tid >> 6;
    const int lane = tid & 63;
    const float R2 = (float)(0.2 * 0.2);        // float32(0.04) = 0x3D23D70A
    const float* qpos = out + POS_OUT_OFF;
    u64* cw = cand[wid];

    for (int qq = 0; qq < 4; ++qq) {
        const int q     = blockIdx.x*16 + wid*4 + qq;
        const int cloud = q >> 11;
        const float* cp = pos + (size_t)cloud * (NPC*3);
        float qx = qpos[q*3+0], qy = qpos[q*3+1], qz = qpos[q*3+2];

        int m = 0;
        for (int c = 0; c < NPC/64; ++c) {
            int j = c*64 + lane;
            float dx = __fsub_rn(cp[j*3+0], qx);
            float dy = __fsub_rn(cp[j*3+1], qy);
            float dz = __fsub_rn(cp[j*3+2], qz);
            float d2 = __fadd_rn(__fadd_rn(__fmul_rn(dx,dx), __fmul_rn(dy,dy)), __fmul_rn(dz,dz));
            bool in = (d2 <= R2);
            u64 mk = __ballot(in);
            if (in) {
                int p = m + __popcll(mk & ((1ull << lane) - 1ull));
                if (p < CAND_MAX) cw[p] = ((u64)__float_as_uint(d2) << 32) | (u32)j;
            }
            m += __popcll(mk);
        }
        if (m > CAND_MAX) m = CAND_MAX;

        double kk[10];
        #pragma unroll
        for (int t = 0; t < 10; ++t) {
            int p = t*64 + lane;
            kk[t] = (p < m) ? __longlong_as_double((long long)cw[p])
                            : __longlong_as_double((long long)INF64);
        }
        int cq = (m < KK) ? m : KK;
        int* nq = nidx + (size_t)q * KK;
        int j0 = 0;
        #pragma unroll 1
        for (int r = 0; r < KK; ++r) {
            double lmin = kk[0];
            #pragma unroll
            for (int t = 1; t < 10; ++t) lmin = fmin(lmin, kk[t]);
            #pragma unroll
            for (int off = 32; off >= 1; off >>= 1)
                lmin = fmin(lmin, __shfl_xor(lmin, off));
            u64 lb = (u64)__double_as_longlong(lmin);
            int j = (int)(u32)lb;
            if (r == 0) j0 = j;                 // center itself (d2=0) is first
            if (lane == 0) nq[r] = (lb == INF64) ? j0 : j;
            #pragma unroll
            for (int t = 0; t < 10; ++t)
                if ((u64)__double_as_longlong(kk[t]) == lb)
                    kk[t] = __longlong_as_double((long long)INF64);
        }
        if (lane == 0) ncnt[q] = cq;
    }
}

// ---------------- Kernel 3: gather + 3-layer MLP + masked max ---------------
// Weights/biases read straight from global with wave-uniform indices ->
// compiler emits s_load broadcasts (no LDS pipe pressure). feat in padded LDS.
__global__ __launch_bounds__(256) void mlp_kernel(const float* __restrict__ x,
                                                  const float* __restrict__ pos,
                                                  const float* __restrict__ W1, const float* __restrict__ b1,
                                                  const float* __restrict__ W2, const float* __restrict__ b2,
                                                  const float* __restrict__ W3, const float* __restrict__ b3,
                                                  const int* __restrict__ nidx, const int* __restrict__ ncnt,
                                                  float* __restrict__ out)
{
    __shared__ float flds[256*69];

    const int tid   = threadIdx.x;
    const int q     = blockIdx.x * 8 + (tid >> 5);
    const int slot  = tid & 31;
    const int cloud = q >> 11;
    const int j     = nidx[q*KK + slot];
    const bool valid = slot < ncnt[q];
    const size_t row = (size_t)cloud * NPC + (size_t)j;

    const float* qp = out + POS_OUT_OFF + (size_t)q*3;
    float qx = qp[0], qy = qp[1], qz = qp[2];

    float* myf = &flds[tid*69];
    {
        const float4* xr = (const float4*)(x + row*CIN);
        #pragma unroll
        for (int i = 0; i < 16; ++i) {
            float4 v = xr[i];
            myf[i*4+0]=v.x; myf[i*4+1]=v.y; myf[i*4+2]=v.z; myf[i*4+3]=v.w;
        }
        myf[64] = __fsub_rn(pos[row*3+0], qx);
        myf[65] = __fsub_rn(pos[row*3+1], qy);
        myf[66] = __fsub_rn(pos[row*3+2], qz);
    }
    // each thread reads only its own flds region: no barrier needed

    float acc[64];
    // ----- layer 1: 67 -> 64, relu -----
    #pragma unroll
    for (int o = 0; o < 64; ++o) acc[o] = b1[o];
    #pragma unroll 2
    for (int i = 0; i < 67; ++i) {
        float f = myf[i];
        const float4* wr = (const float4*)(W1 + i*64);
        #pragma unroll
        for (int o4 = 0; o4 < 16; ++o4) {
            float4 wv = wr[o4];
            acc[o4*4+0] = fmaf(f, wv.x, acc[o4*4+0]);
            acc[o4*4+1] = fmaf(f, wv.y, acc[o4*4+1]);
            acc[o4*4+2] = fmaf(f, wv.z, acc[o4*4+2]);
            acc[o4*4+3] = fmaf(f, wv.w, acc[o4*4+3]);
        }
    }
    #pragma unroll
    for (int o = 0; o < 64; ++o) myf[o] = fmaxf(acc[o], 0.0f);

    // ----- layer 2: 64 -> 64, relu -----
    #pragma unroll
    for (int o = 0; o < 64; ++o) acc[o] = b2[o];
    #pragma unroll 2
    for (int i = 0; i < 64; ++i) {
        float f = myf[i];
        const float4* wr = (const float4*)(W2 + i*64);
        #pragma unroll
        for (int o4 = 0; o4 < 16; ++o4) {
            float4 wv = wr[o4];
            acc[o4*4+0] = fmaf(f, wv.x, acc[o4*4+0]);
            acc[o4*4+1] = fmaf(f, wv.y, acc[o4*4+1]);
            acc[o4*4+2] = fmaf(f, wv.z, acc[o4*4+2]);
            acc[o4*4+3] = fmaf(f, wv.w, acc[o4*4+3]);
        }
    }
    #pragma unroll
    for (int o = 0; o < 64; ++o) myf[o] = fmaxf(acc[o], 0.0f);

    // ----- layer 3: 64 -> 128 (two halves), mask, max over 32 slots -----
    float* orow = out + (size_t)q*128;
    const float NEGINF = __int_as_float(0xff800000);
    for (int h = 0; h < 2; ++h) {
        #pragma unroll
        for (int o = 0; o < 64; ++o) acc[o] = b3[h*64 + o];
        const float* w3h = W3 + h*64;
        #pragma unroll 2
        for (int i = 0; i < 64; ++i) {
            float f = myf[i];
            const float4* wr = (const float4*)(w3h + i*128);
            #pragma unroll
            for (int o4 = 0; o4 < 16; ++o4) {
                float4 wv = wr[o4];
                acc[o4*4+0] = fmaf(f, wv.x, acc[o4*4+0]);
                acc[o4*4+1] = fmaf(f, wv.y, acc[o4*4+1]);
                acc[o4*4+2] = fmaf(f, wv.z, acc[o4*4+2]);
                acc[o4*4+3] = fmaf(f, wv.w, acc[o4*4+3]);
            }
        }
        #pragma unroll
        for (int o = 0; o < 64; ++o) if (!valid) acc[o] = NEGINF;
        #pragma unroll
        for (int off = 16; off >= 1; off >>= 1) {
            #pragma unroll
            for (int o = 0; o < 64; ++o) acc[o] = fmaxf(acc[o], __shfl_xor(acc[o], off));
        }
        if (slot == 0) {
            #pragma unroll
            for (int o = 0; o < 64; o += 4) {
                float4 v = make_float4(acc[o], acc[o+1], acc[o+2], acc[o+3]);
                *(float4*)&orow[h*64+o] = v;
            }
        }
    }
}

// ------------------------------- launcher -----------------------------------
extern "C" void kernel_launch(void* const* d_in, const int* in_sizes, int n_in,
                              void* d_out, int out_size, void* d_ws, size_t ws_size,
                              hipStream_t stream) {
    const float* x   = (const float*)d_in[0];
    const float* pos = (const float*)d_in[1];
    // d_in[2]=batch (implicit), d_in[3]=num_samples (K=32 hardcoded)
    const float* W1 = (const float*)d_in[4];
    const float* b1 = (const float*)d_in[5];
    const float* W2 = (const float*)d_in[6];
    const float* b2 = (const float*)d_in[7];
    const float* W3 = (const float*)d_in[8];
    const float* b3 = (const float*)d_in[9];
    float* out = (float*)d_out;

    int* nidx = (int*)d_ws;                  // NQ*KK ints (2 MiB)
    int* ncnt = nidx + (size_t)NQ*KK;        // NQ ints

    hipLaunchKernelGGL(fps_kernel,    dim3(NB),      dim3(512), 0, stream, pos, out);
    hipLaunchKernelGGL(radius_kernel, dim3(NQ/16),   dim3(256), 0, stream, pos, out, nidx, ncnt);
    hipLaunchKernelGGL(mlp_kernel,    dim3(NQ/8),    dim3(256), 0, stream,
                       x, pos, W1, b1, W2, b2, W3, b3, nidx, ncnt, out);
}

// Round 3
// 2516.518 us; speedup vs baseline: 1.3129x; 1.0022x over previous
//
#include <hip/hip_runtime.h>

typedef unsigned long long u64;
typedef unsigned int u32;
typedef float v2f __attribute__((ext_vector_type(2)));

#define NB   8
#define NPC  8192
#define SS   2048
#define KK   32
#define CIN  64
#define NQ   (NB*SS)              // 16384
#define POS_OUT_OFF   (NQ*128)
#define BATCH_OUT_OFF (NQ*128 + NQ*3)
#define INF64 0x7ff0000000000000ULL

// Packed f32 ops via inline asm: IEEE round-to-nearest-even, bit-identical to
// scalar v_add_f32/v_mul_f32 per half; immune to -ffp-contract fusing.
__device__ __forceinline__ v2f pk_add(v2f a, v2f b) {
    v2f r; asm("v_pk_add_f32 %0, %1, %2" : "=v"(r) : "v"(a), "v"(b)); return r;
}
__device__ __forceinline__ v2f pk_mul(v2f a, v2f b) {
    v2f r; asm("v_pk_mul_f32 %0, %1, %2" : "=v"(r) : "v"(a), "v"(b)); return r;
}
// key = (dist_bits<<32) | ~idx, viewed as f64. dist_bits <= 0x7f800000 so the
// f64 exponent field is < 2047: never NaN/Inf -> v_max_f64 == exact u64 max.
__device__ __forceinline__ double mkkey(float m, u32 ni) {
    return __longlong_as_double((long long)(((u64)__float_as_uint(m) << 32) | (u64)ni));
}

// ---------------- Kernel 1: exact farthest point sampling -------------------
// One block/cloud, 512 thr x 16 pts. No global stores in the step loop (winner
// history kept in LDS); packed-f32 distance update; f64-key max reduction.
__global__ __launch_bounds__(512) void fps_kernel(const float* __restrict__ pos,
                                                  float* __restrict__ out)
{
    __shared__ float lp[NPC*3];
    __shared__ double red[2][8];
    __shared__ unsigned short hist[SS];
    const int tid  = threadIdx.x;
    const int wid  = tid >> 6;
    const int lane = tid & 63;
    const int cloud = blockIdx.x;
    const float* cp = pos + (size_t)cloud * (NPC*3);

    {   // stage cloud positions into LDS (coalesced float4)
        const float4* s4 = (const float4*)cp;
        float4* d4 = (float4*)lp;
        #pragma unroll
        for (int i = 0; i < 12; ++i) d4[tid + i*512] = s4[tid + i*512];
    }
    __syncthreads();

    v2f px[8], py[8], pz[8], mind[8];
    u32 inv[16];
    const float finf = __int_as_float(0x7f800000);
    #pragma unroll
    for (int k = 0; k < 8; ++k) {
        int j = tid*16 + 2*k;
        px[k] = (v2f){lp[j*3+0], lp[j*3+3]};
        py[k] = (v2f){lp[j*3+1], lp[j*3+4]};
        pz[k] = (v2f){lp[j*3+2], lp[j*3+5]};
        mind[k] = (v2f){finf, finf};
    }
    #pragma unroll
    for (int k = 0; k < 16; ++k) inv[k] = ~(u32)(tid*16 + k);

    float cx = lp[0], cy = lp[1], cz = lp[2];
    u32 widx = 0;

    for (int s = 0; s < SS; ++s) {
        if (tid == 0) hist[s] = (unsigned short)widx;
        // p + (-c) rounds identically to p - c (exact sign-flip on c)
        v2f ncx = (v2f){-cx,-cx}, ncy = (v2f){-cy,-cy}, ncz = (v2f){-cz,-cz};
        double kd[16];
        #pragma unroll
        for (int k = 0; k < 8; ++k) {
            v2f dx = pk_add(px[k], ncx);
            v2f dy = pk_add(py[k], ncy);
            v2f dz = pk_add(pz[k], ncz);
            v2f d  = pk_add(pk_add(pk_mul(dx,dx), pk_mul(dy,dy)), pk_mul(dz,dz));
            float m0 = fminf(mind[k].x, d.x);
            float m1 = fminf(mind[k].y, d.y);
            mind[k].x = m0; mind[k].y = m1;
            kd[2*k]   = mkkey(m0, inv[2*k]);
            kd[2*k+1] = mkkey(m1, inv[2*k+1]);
        }
        #pragma unroll
        for (int st = 8; st >= 1; st >>= 1) {
            #pragma unroll
            for (int k = 0; k < st; ++k) kd[k] = fmax(kd[k], kd[k+st]);
        }
        double wk = kd[0];
        #pragma unroll
        for (int off = 32; off >= 1; off >>= 1)
            wk = fmax(wk, __shfl_xor(wk, off));
        if (lane == 0) red[s&1][wid] = wk;
        __syncthreads();
        const double* rb = red[s&1];
        double g = fmax(fmax(fmax(rb[0],rb[1]), fmax(rb[2],rb[3])),
                        fmax(fmax(rb[4],rb[5]), fmax(rb[6],rb[7])));
        widx = ~(u32)((u64)__double_as_longlong(g));
        cx = lp[widx*3+0]; cy = lp[widx*3+1]; cz = lp[widx*3+2];
    }
    __syncthreads();

    float* qout = out + POS_OUT_OFF   + (size_t)cloud * SS * 3;
    float* bout = out + BATCH_OUT_OFF + (size_t)cloud * SS;
    for (int s = tid; s < SS; s += 512) {
        u32 w = hist[s];
        qout[s*3+0] = lp[w*3+0];
        qout[s*3+1] = lp[w*3+1];
        qout[s*3+2] = lp[w*3+2];
        bout[s] = (float)cloud;
    }
}

// ---------------- Kernel 2: radius / 32 smallest-d2 selection ---------------
// Global-direct scan (cloud is L2-resident across the 64 blocks sharing it),
// ballot-compacted candidates in LDS, f64-key min extraction.
#define CAND_MAX 640
__global__ __launch_bounds__(256) void radius_kernel(const float* __restrict__ pos,
                                                     const float* __restrict__ out,
                                                     int* __restrict__ nidx,
                                                     int* __restrict__ ncnt)
{
    __shared__ u64 cand[4][CAND_MAX];
    const int tid  = threadIdx.x;
    const int wid  = tid >> 6;
    const int lane = tid & 63;
    const float R2 = (float)(0.2 * 0.2);        // float32(0.04) = 0x3D23D70A
    const float* qpos = out + POS_OUT_OFF;
    u64* cw = cand[wid];

    for (int qq = 0; qq < 4; ++qq) {
        const int q     = blockIdx.x*16 + wid*4 + qq;
        const int cloud = q >> 11;
        const float* cp = pos + (size_t)cloud * (NPC*3);
        float qx = qpos[q*3+0], qy = qpos[q*3+1], qz = qpos[q*3+2];

        int m = 0;
        for (int c = 0; c < NPC/64; ++c) {
            int j = c*64 + lane;
            float dx = __fsub_rn(cp[j*3+0], qx);
            float dy = __fsub_rn(cp[j*3+1], qy);
            float dz = __fsub_rn(cp[j*3+2], qz);
            float d2 = __fadd_rn(__fadd_rn(__fmul_rn(dx,dx), __fmul_rn(dy,dy)), __fmul_rn(dz,dz));
            bool in = (d2 <= R2);
            u64 mk = __ballot(in);
            if (in) {
                int p = m + __popcll(mk & ((1ull << lane) - 1ull));
                if (p < CAND_MAX) cw[p] = ((u64)__float_as_uint(d2) << 32) | (u32)j;
            }
            m += __popcll(mk);
        }
        if (m > CAND_MAX) m = CAND_MAX;

        double kk[10];
        #pragma unroll
        for (int t = 0; t < 10; ++t) {
            int p = t*64 + lane;
            kk[t] = (p < m) ? __longlong_as_double((long long)cw[p])
                            : __longlong_as_double((long long)INF64);
        }
        int cq = (m < KK) ? m : KK;
        int* nq = nidx + (size_t)q * KK;
        int j0 = 0;
        #pragma unroll 1
        for (int r = 0; r < KK; ++r) {
            double lmin = kk[0];
            #pragma unroll
            for (int t = 1; t < 10; ++t) lmin = fmin(lmin, kk[t]);
            #pragma unroll
            for (int off = 32; off >= 1; off >>= 1)
                lmin = fmin(lmin, __shfl_xor(lmin, off));
            u64 lb = (u64)__double_as_longlong(lmin);
            int j = (int)(u32)lb;
            if (r == 0) j0 = j;                 // center itself (d2=0) is first
            if (lane == 0) nq[r] = (lb == INF64) ? j0 : j;
            #pragma unroll
            for (int t = 0; t < 10; ++t)
                if ((u64)__double_as_longlong(kk[t]) == lb)
                    kk[t] = __longlong_as_double((long long)INF64);
        }
        if (lane == 0) ncnt[q] = cq;
    }
}

// ---------------- Kernel 3: gather + 3-layer MLP + masked max ---------------
// Weights/biases read straight from global with wave-uniform indices ->
// compiler emits s_load broadcasts (no LDS pipe pressure). feat in padded LDS.
__global__ __launch_bounds__(256) void mlp_kernel(const float* __restrict__ x,
                                                  const float* __restrict__ pos,
                                                  const float* __restrict__ W1, const float* __restrict__ b1,
                                                  const float* __restrict__ W2, const float* __restrict__ b2,
                                                  const float* __restrict__ W3, const float* __restrict__ b3,
                                                  const int* __restrict__ nidx, const int* __restrict__ ncnt,
                                                  float* __restrict__ out)
{
    __shared__ float flds[256*69];

    const int tid   = threadIdx.x;
    const int q     = blockIdx.x * 8 + (tid >> 5);
    const int slot  = tid & 31;
    const int cloud = q >> 11;
    const int j     = nidx[q*KK + slot];
    const bool valid = slot < ncnt[q];
    const size_t row = (size_t)cloud * NPC + (size_t)j;

    const float* qp = out + POS_OUT_OFF + (size_t)q*3;
    float qx = qp[0], qy = qp[1], qz = qp[2];

    float* myf = &flds[tid*69];
    {
        const float4* xr = (const float4*)(x + row*CIN);
        #pragma unroll
        for (int i = 0; i < 16; ++i) {
            float4 v = xr[i];
            myf[i*4+0]=v.x; myf[i*4+1]=v.y; myf[i*4+2]=v.z; myf[i*4+3]=v.w;
        }
        myf[64] = __fsub_rn(pos[row*3+0], qx);
        myf[65] = __fsub_rn(pos[row*3+1], qy);
        myf[66] = __fsub_rn(pos[row*3+2], qz);
    }
    // each thread reads only its own flds region: no barrier needed

    float acc[64];
    // ----- layer 1: 67 -> 64, relu -----
    #pragma unroll
    for (int o = 0; o < 64; ++o) acc[o] = b1[o];
    #pragma unroll 2
    for (int i = 0; i < 67; ++i) {
        float f = myf[i];
        const float4* wr = (const float4*)(W1 + i*64);
        #pragma unroll
        for (int o4 = 0; o4 < 16; ++o4) {
            float4 wv = wr[o4];
            acc[o4*4+0] = fmaf(f, wv.x, acc[o4*4+0]);
            acc[o4*4+1] = fmaf(f, wv.y, acc[o4*4+1]);
            acc[o4*4+2] = fmaf(f, wv.z, acc[o4*4+2]);
            acc[o4*4+3] = fmaf(f, wv.w, acc[o4*4+3]);
        }
    }
    #pragma unroll
    for (int o = 0; o < 64; ++o) myf[o] = fmaxf(acc[o], 0.0f);

    // ----- layer 2: 64 -> 64, relu -----
    #pragma unroll
    for (int o = 0; o < 64; ++o) acc[o] = b2[o];
    #pragma unroll 2
    for (int i = 0; i < 64; ++i) {
        float f = myf[i];
        const float4* wr = (const float4*)(W2 + i*64);
        #pragma unroll
        for (int o4 = 0; o4 < 16; ++o4) {
            float4 wv = wr[o4];
            acc[o4*4+0] = fmaf(f, wv.x, acc[o4*4+0]);
            acc[o4*4+1] = fmaf(f, wv.y, acc[o4*4+1]);
            acc[o4*4+2] = fmaf(f, wv.z, acc[o4*4+2]);
            acc[o4*4+3] = fmaf(f, wv.w, acc[o4*4+3]);
        }
    }
    #pragma unroll
    for (int o = 0; o < 64; ++o) myf[o] = fmaxf(acc[o], 0.0f);

    // ----- layer 3: 64 -> 128 (two halves), mask, max over 32 slots -----
    float* orow = out + (size_t)q*128;
    const float NEGINF = __int_as_float(0xff800000);
    for (int h = 0; h < 2; ++h) {
        #pragma unroll
        for (int o = 0; o < 64; ++o) acc[o] = b3[h*64 + o];
        const float* w3h = W3 + h*64;
        #pragma unroll 2
        for (int i = 0; i < 64; ++i) {
            float f = myf[i];
            const float4* wr = (const float4*)(w3h + i*128);
            #pragma unroll
            for (int o4 = 0; o4 < 16; ++o4) {
                float4 wv = wr[o4];
                acc[o4*4+0] = fmaf(f, wv.x, acc[o4*4+0]);
                acc[o4*4+1] = fmaf(f, wv.y, acc[o4*4+1]);
                acc[o4*4+2] = fmaf(f, wv.z, acc[o4*4+2]);
                acc[o4*4+3] = fmaf(f, wv.w, acc[o4*4+3]);
            }
        }
        #pragma unroll
        for (int o = 0; o < 64; ++o) if (!valid) acc[o] = NEGINF;
        #pragma unroll
        for (int off = 16; off >= 1; off >>= 1) {
            #pragma unroll
            for (int o = 0; o < 64; ++o) acc[o] = fmaxf(acc[o], __shfl_xor(acc[o], off));
        }
        if (slot == 0) {
            #pragma unroll
            for (int o = 0; o < 64; o += 4) {
                float4 v = make_float4(acc[o], acc[o+1], acc[o+2], acc[o+3]);
                *(float4*)&orow[h*64+o] = v;
            }
        }
    }
}

// ------------------------------- launcher -----------------------------------
extern "C" void kernel_launch(void* const* d_in, const int* in_sizes, int n_in,
                              void* d_out, int out_size, void* d_ws, size_t ws_size,
                              hipStream_t stream) {
    const float* x   = (const float*)d_in[0];
    const float* pos = (const float*)d_in[1];
    // d_in[2]=batch (implicit), d_in[3]=num_samples (K=32 hardcoded)
    const float* W1 = (const float*)d_in[4];
    const float* b1 = (const float*)d_in[5];
    const float* W2 = (const float*)d_in[6];
    const float* b2 = (const float*)d_in[7];
    const float* W3 = (const float*)d_in[8];
    const float* b3 = (const float*)d_in[9];
    float* out = (float*)d_out;

    int* nidx = (int*)d_ws;                  // NQ*KK ints (2 MiB)
    int* ncnt = nidx + (size_t)NQ*KK;        // NQ ints

    hipLaunchKernelGGL(fps_kernel,    dim3(NB),      dim3(512), 0, stream, pos, out);
    hipLaunchKernelGGL(radius_kernel, dim3(NQ/16),   dim3(256), 0, stream, pos, out, nidx, ncnt);
    hipLaunchKernelGGL(mlp_kernel,    dim3(NQ/8),    dim3(256), 0, stream,
                       x, pos, W1, b1, W2, b2, W3, b3, nidx, ncnt, out);
}

// Round 4
// 2514.347 us; speedup vs baseline: 1.3140x; 1.0009x over previous
//
#include <hip/hip_runtime.h>

typedef unsigned long long u64;
typedef unsigned int u32;
typedef float v2f __attribute__((ext_vector_type(2)));

#define NB   8
#define NPC  8192
#define SS   2048
#define KK   32
#define CIN  64
#define NQ   (NB*SS)              // 16384
#define POS_OUT_OFF   (NQ*128)
#define BATCH_OUT_OFF (NQ*128 + NQ*3)
#define INF64 0x7ff0000000000000ULL

// Packed f32 ops via inline asm: IEEE round-to-nearest-even, bit-identical to
// scalar v_add_f32/v_mul_f32 per half; immune to -ffp-contract fusing.
__device__ __forceinline__ v2f pk_add(v2f a, v2f b) {
    v2f r; asm("v_pk_add_f32 %0, %1, %2" : "=v"(r) : "v"(a), "v"(b)); return r;
}
__device__ __forceinline__ v2f pk_mul(v2f a, v2f b) {
    v2f r; asm("v_pk_mul_f32 %0, %1, %2" : "=v"(r) : "v"(a), "v"(b)); return r;
}
// key = (dist_bits<<32) | ~idx, viewed as f64. dist_bits <= 0x7f800000 so the
// f64 exponent field is < 2047: never NaN/Inf -> v_max_f64 == exact u64 max.
__device__ __forceinline__ double mkkey(float m, u32 ni) {
    return __longlong_as_double((long long)(((u64)__float_as_uint(m) << 32) | (u64)ni));
}

// ---------------- Kernel 1: exact farthest point sampling -------------------
// One block/cloud, 512 thr x 16 pts. No global stores in the step loop (winner
// history kept in LDS); packed-f32 distance update; f64-key max reduction.
__global__ __launch_bounds__(512) void fps_kernel(const float* __restrict__ pos,
                                                  float* __restrict__ out)
{
    __shared__ float lp[NPC*3];
    __shared__ double red[2][8];
    __shared__ unsigned short hist[SS];
    const int tid  = threadIdx.x;
    const int wid  = tid >> 6;
    const int lane = tid & 63;
    const int cloud = blockIdx.x;
    const float* cp = pos + (size_t)cloud * (NPC*3);

    {   // stage cloud positions into LDS (coalesced float4)
        const float4* s4 = (const float4*)cp;
        float4* d4 = (float4*)lp;
        #pragma unroll
        for (int i = 0; i < 12; ++i) d4[tid + i*512] = s4[tid + i*512];
    }
    __syncthreads();

    v2f px[8], py[8], pz[8], mind[8];
    u32 inv[16];
    const float finf = __int_as_float(0x7f800000);
    #pragma unroll
    for (int k = 0; k < 8; ++k) {
        int j = tid*16 + 2*k;
        px[k] = (v2f){lp[j*3+0], lp[j*3+3]};
        py[k] = (v2f){lp[j*3+1], lp[j*3+4]};
        pz[k] = (v2f){lp[j*3+2], lp[j*3+5]};
        mind[k] = (v2f){finf, finf};
    }
    #pragma unroll
    for (int k = 0; k < 16; ++k) inv[k] = ~(u32)(tid*16 + k);

    float cx = lp[0], cy = lp[1], cz = lp[2];
    u32 widx = 0;

    for (int s = 0; s < SS; ++s) {
        if (tid == 0) hist[s] = (unsigned short)widx;
        // p + (-c) rounds identically to p - c (exact sign-flip on c)
        v2f ncx = (v2f){-cx,-cx}, ncy = (v2f){-cy,-cy}, ncz = (v2f){-cz,-cz};
        double kd[16];
        #pragma unroll
        for (int k = 0; k < 8; ++k) {
            v2f dx = pk_add(px[k], ncx);
            v2f dy = pk_add(py[k], ncy);
            v2f dz = pk_add(pz[k], ncz);
            v2f d  = pk_add(pk_add(pk_mul(dx,dx), pk_mul(dy,dy)), pk_mul(dz,dz));
            float m0 = fminf(mind[k].x, d.x);
            float m1 = fminf(mind[k].y, d.y);
            mind[k].x = m0; mind[k].y = m1;
            kd[2*k]   = mkkey(m0, inv[2*k]);
            kd[2*k+1] = mkkey(m1, inv[2*k+1]);
        }
        #pragma unroll
        for (int st = 8; st >= 1; st >>= 1) {
            #pragma unroll
            for (int k = 0; k < st; ++k) kd[k] = fmax(kd[k], kd[k+st]);
        }
        double wk = kd[0];
        #pragma unroll
        for (int off = 32; off >= 1; off >>= 1)
            wk = fmax(wk, __shfl_xor(wk, off));
        if (lane == 0) red[s&1][wid] = wk;
        __syncthreads();
        const double* rb = red[s&1];
        double g = fmax(fmax(fmax(rb[0],rb[1]), fmax(rb[2],rb[3])),
                        fmax(fmax(rb[4],rb[5]), fmax(rb[6],rb[7])));
        widx = ~(u32)((u64)__double_as_longlong(g));
        cx = lp[widx*3+0]; cy = lp[widx*3+1]; cz = lp[widx*3+2];
    }
    __syncthreads();

    float* qout = out + POS_OUT_OFF   + (size_t)cloud * SS * 3;
    float* bout = out + BATCH_OUT_OFF + (size_t)cloud * SS;
    for (int s = tid; s < SS; s += 512) {
        u32 w = hist[s];
        qout[s*3+0] = lp[w*3+0];
        qout[s*3+1] = lp[w*3+1];
        qout[s*3+2] = lp[w*3+2];
        bout[s] = (float)cloud;
    }
}

// ---------------- Kernel 2: radius / 32 smallest-d2 selection ---------------
// Global-direct scan (cloud is L2-resident across the 64 blocks sharing it),
// ballot-compacted candidates in LDS, f64-key min extraction.
#define CAND_MAX 640
__global__ __launch_bounds__(256) void radius_kernel(const float* __restrict__ pos,
                                                     const float* __restrict__ out,
                                                     int* __restrict__ nidx,
                                                     int* __restrict__ ncnt)
{
    __shared__ u64 cand[4][CAND_MAX];
    const int tid  = threadIdx.x;
    const int wid  = tid >> 6;
    const int lane = tid & 63;
    const float R2 = (float)(0.2 * 0.2);        // float32(0.04) = 0x3D23D70A
    const float* qpos = out + POS_OUT_OFF;
    u64* cw = cand[wid];

    for (int qq = 0; qq < 4; ++qq) {
        const int q     = blockIdx.x*16 + wid*4 + qq;
        const int cloud = q >> 11;
        const float* cp = pos + (size_t)cloud * (NPC*3);
        float qx = qpos[q*3+0], qy = qpos[q*3+1], qz = qpos[q*3+2];

        int m = 0;
        for (int c = 0; c < NPC/64; ++c) {
            int j = c*64 + lane;
            float dx = __fsub_rn(cp[j*3+0], qx);
            float dy = __fsub_rn(cp[j*3+1], qy);
            float dz = __fsub_rn(cp[j*3+2], qz);
            float d2 = __fadd_rn(__fadd_rn(__fmul_rn(dx,dx), __fmul_rn(dy,dy)), __fmul_rn(dz,dz));
            bool in = (d2 <= R2);
            u64 mk = __ballot(in);
            if (in) {
                int p = m + __popcll(mk & ((1ull << lane) - 1ull));
                if (p < CAND_MAX) cw[p] = ((u64)__float_as_uint(d2) << 32) | (u32)j;
            }
            m += __popcll(mk);
        }
        if (m > CAND_MAX) m = CAND_MAX;

        double kk[10];
        #pragma unroll
        for (int t = 0; t < 10; ++t) {
            int p = t*64 + lane;
            kk[t] = (p < m) ? __longlong_as_double((long long)cw[p])
                            : __longlong_as_double((long long)INF64);
        }
        int cq = (m < KK) ? m : KK;
        int* nq = nidx + (size_t)q * KK;
        int j0 = 0;
        #pragma unroll 1
        for (int r = 0; r < KK; ++r) {
            double lmin = kk[0];
            #pragma unroll
            for (int t = 1; t < 10; ++t) lmin = fmin(lmin, kk[t]);
            #pragma unroll
            for (int off = 32; off >= 1; off >>= 1)
                lmin = fmin(lmin, __shfl_xor(lmin, off));
            u64 lb = (u64)__double_as_longlong(lmin);
            int j = (int)(u32)lb;
            if (r == 0) j0 = j;                 // center itself (d2=0) is first
            if (lane == 0) nq[r] = (lb == INF64) ? j0 : j;
            #pragma unroll
            for (int t = 0; t < 10; ++t)
                if ((u64)__double_as_longlong(kk[t]) == lb)
                    kk[t] = __longlong_as_double((long long)INF64);
        }
        if (lane == 0) ncnt[q] = cq;
    }
}

// ---------------- Kernel 3: gather + 3-layer MLP + masked max ---------------
// Weights/biases read straight from global with wave-uniform indices ->
// compiler emits s_load broadcasts (no LDS pipe pressure). feat in padded LDS.
__global__ __launch_bounds__(256) void mlp_kernel(const float* __restrict__ x,
                                                  const float* __restrict__ pos,
                                                  const float* __restrict__ W1, const float* __restrict__ b1,
                                                  const float* __restrict__ W2, const float* __restrict__ b2,
                                                  const float* __restrict__ W3, const float* __restrict__ b3,
                                                  const int* __restrict__ nidx, const int* __restrict__ ncnt,
                                                  float* __restrict__ out)
{
    __shared__ float flds[256*69];

    const int tid   = threadIdx.x;
    const int q     = blockIdx.x * 8 + (tid >> 5);
    const int slot  = tid & 31;
    const int cloud = q >> 11;
    const int j     = nidx[q*KK + slot];
    const bool valid = slot < ncnt[q];
    const size_t row = (size_t)cloud * NPC + (size_t)j;

    const float* qp = out + POS_OUT_OFF + (size_t)q*3;
    float qx = qp[0], qy = qp[1], qz = qp[2];

    float* myf = &flds[tid*69];
    {
        const float4* xr = (const float4*)(x + row*CIN);
        #pragma unroll
        for (int i = 0; i < 16; ++i) {
            float4 v = xr[i];
            myf[i*4+0]=v.x; myf[i*4+1]=v.y; myf[i*4+2]=v.z; myf[i*4+3]=v.w;
        }
        myf[64] = __fsub_rn(pos[row*3+0], qx);
        myf[65] = __fsub_rn(pos[row*3+1], qy);
        myf[66] = __fsub_rn(pos[row*3+2], qz);
    }
    // each thread reads only its own flds region: no barrier needed

    float acc[64];
    // ----- layer 1: 67 -> 64, relu -----
    #pragma unroll
    for (int o = 0; o < 64; ++o) acc[o] = b1[o];
    #pragma unroll 2
    for (int i = 0; i < 67; ++i) {
        float f = myf[i];
        const float4* wr = (const float4*)(W1 + i*64);
        #pragma unroll
        for (int o4 = 0; o4 < 16; ++o4) {
            float4 wv = wr[o4];
            acc[o4*4+0] = fmaf(f, wv.x, acc[o4*4+0]);
            acc[o4*4+1] = fmaf(f, wv.y, acc[o4*4+1]);
            acc[o4*4+2] = fmaf(f, wv.z, acc[o4*4+2]);
            acc[o4*4+3] = fmaf(f, wv.w, acc[o4*4+3]);
        }
    }
    #pragma unroll
    for (int o = 0; o < 64; ++o) myf[o] = fmaxf(acc[o], 0.0f);

    // ----- layer 2: 64 -> 64, relu -----
    #pragma unroll
    for (int o = 0; o < 64; ++o) acc[o] = b2[o];
    #pragma unroll 2
    for (int i = 0; i < 64; ++i) {
        float f = myf[i];
        const float4* wr = (const float4*)(W2 + i*64);
        #pragma unroll
        for (int o4 = 0; o4 < 16; ++o4) {
            float4 wv = wr[o4];
            acc[o4*4+0] = fmaf(f, wv.x, acc[o4*4+0]);
            acc[o4*4+1] = fmaf(f, wv.y, acc[o4*4+1]);
            acc[o4*4+2] = fmaf(f, wv.z, acc[o4*4+2]);
            acc[o4*4+3] = fmaf(f, wv.w, acc[o4*4+3]);
        }
    }
    #pragma unroll
    for (int o = 0; o < 64; ++o) myf[o] = fmaxf(acc[o], 0.0f);

    // ----- layer 3: 64 -> 128 (two halves), mask, max over 32 slots -----
    float* orow = out + (size_t)q*128;
    const float NEGINF = __int_as_float(0xff800000);
    for (int h = 0; h < 2; ++h) {
        #pragma unroll
        for (int o = 0; o < 64; ++o) acc[o] = b3[h*64 + o];
        const float* w3h = W3 + h*64;
        #pragma unroll 2
        for (int i = 0; i < 64; ++i) {
            float f = myf[i];
            const float4* wr = (const float4*)(w3h + i*128);
            #pragma unroll
            for (int o4 = 0; o4 < 16; ++o4) {
                float4 wv = wr[o4];
                acc[o4*4+0] = fmaf(f, wv.x, acc[o4*4+0]);
                acc[o4*4+1] = fmaf(f, wv.y, acc[o4*4+1]);
                acc[o4*4+2] = fmaf(f, wv.z, acc[o4*4+2]);
                acc[o4*4+3] = fmaf(f, wv.w, acc[o4*4+3]);
            }
        }
        #pragma unroll
        for (int o = 0; o < 64; ++o) if (!valid) acc[o] = NEGINF;
        #pragma unroll
        for (int off = 16; off >= 1; off >>= 1) {
            #pragma unroll
            for (int o = 0; o < 64; ++o) acc[o] = fmaxf(acc[o], __shfl_xor(acc[o], off));
        }
        if (slot == 0) {
            #pragma unroll
            for (int o = 0; o < 64; o += 4) {
                float4 v = make_float4(acc[o], acc[o+1], acc[o+2], acc[o+3]);
                *(float4*)&orow[h*64+o] = v;
            }
        }
    }
}

// ------------------------------- launcher -----------------------------------
extern "C" void kernel_launch(void* const* d_in, const int* in_sizes, int n_in,
                              void* d_out, int out_size, void* d_ws, size_t ws_size,
                              hipStream_t stream) {
    const float* x   = (const float*)d_in[0];
    const float* pos = (const float*)d_in[1];
    // d_in[2]=batch (implicit), d_in[3]=num_samples (K=32 hardcoded)
    const float* W1 = (const float*)d_in[4];
    const float* b1 = (const float*)d_in[5];
    const float* W2 = (const float*)d_in[6];
    const float* b2 = (const float*)d_in[7];
    const float* W3 = (const float*)d_in[8];
    const float* b3 = (const float*)d_in[9];
    float* out = (float*)d_out;

    int* nidx = (int*)d_ws;                  // NQ*KK ints (2 MiB)
    int* ncnt = nidx + (size_t)NQ*KK;        // NQ ints

    hipLaunchKernelGGL(fps_kernel,    dim3(NB),      dim3(512), 0, stream, pos, out);
    hipLaunchKernelGGL(radius_kernel, dim3(NQ/16),   dim3(256), 0, stream, pos, out, nidx, ncnt);
    hipLaunchKernelGGL(mlp_kernel,    dim3(NQ/8),    dim3(256), 0, stream,
                       x, pos, W1, b1, W2, b2, W3, b3, nidx, ncnt, out);
}